// Round 11
// baseline (163.458 us; speedup 1.0000x reference)
//
#include <hip/hip_runtime.h>
#include <hip/hip_bf16.h>
#include <math.h>

#define B_ 2
#define S_ 1024
#define H_ 1024
#define NH_ 16
#define D_ 64
#define VOCAB 129

#define PSTR 72     // P LDS row stride (bf16); 144 B rows, 16B-aligned bf16x8 reads
#define QRSTR 136   // Qr/Pb LDS row stride (bf16); 272 B rows, 16B-aligned

typedef __bf16 bf16_t;
typedef __bf16 bf16x8 __attribute__((ext_vector_type(8)));
typedef __bf16 bf16x4 __attribute__((ext_vector_type(4)));
typedef float f32x4 __attribute__((ext_vector_type(4)));

#define MFMA16(a, b, c) __builtin_amdgcn_mfma_f32_16x16x32_bf16(a, b, c, 0, 0, 0)
#define LGKM_FENCE() __asm__ volatile("s_waitcnt lgkmcnt(0)" ::: "memory")
#define BARRIER_RAW() __asm__ volatile("s_barrier" ::: "memory")
#define VMCNT(n) __asm__ volatile("s_waitcnt vmcnt(" #n ")" ::: "memory")
#define GLL(gp, lp) __builtin_amdgcn_global_load_lds( \
    (const __attribute__((address_space(1))) void*)(gp), \
    (__attribute__((address_space(3))) void*)(lp), 16, 0, 0)

// ---------------------------------------------------------------------------
// Fused: blocks [0,5120) cast hidden/Wq/Wk/Wv f32->bf16; blocks [5120,5156)
// build the sinusoid tables.  (r17 lesson: fusing the cast INTO proj via
// reg-staging lost 10 us — GLL direct-to-LDS is mandatory for proj.)
// ---------------------------------------------------------------------------
__global__ __launch_bounds__(256) void cast_tab_kernel(
        const float* __restrict__ hidden, const float* __restrict__ Wq,
        const float* __restrict__ Wk, const float* __restrict__ Wv,
        bf16_t* __restrict__ hidbf, bf16_t* __restrict__ wbf,
        float* __restrict__ tab, bf16_t* __restrict__ tab_bf,
        bf16_t* __restrict__ tabT_bf) {
    const int bid = blockIdx.x;
    const int tid = threadIdx.x;
    if (bid >= 5120) {
        int r = (bid - 5120) * 4 + (tid >> 6);   // 0..143
        int d = tid & 63;
        float val = 0.f;
        if (r < VOCAB) {
            int p = d >> 1;
            float div = __expf((float)(2 * p) * (-logf(10000.0f) / (float)D_));
            float ang = (float)r * div;
            val = (d & 1) ? cosf(ang) : sinf(ang);
            tab[r * D_ + d] = val;
        }
        tab_bf[r * D_ + d] = (bf16_t)val;
        if (r < 128) tabT_bf[d * 128 + r] = (bf16_t)val;
        return;
    }
    const int i = bid * 256 + tid;   // float4 index, < 1280K
    const int HID4 = 512 * 1024, W4 = 256 * 1024;
    const float* src;
    bf16_t* dst;
    int off;
    if (i < HID4)            { src = hidden; dst = hidbf;             off = i; }
    else if (i < HID4 + W4)  { src = Wq;     dst = wbf;               off = i - HID4; }
    else if (i < HID4 + 2*W4){ src = Wk;     dst = wbf + 1024*1024;   off = i - HID4 - W4; }
    else                     { src = Wv;     dst = wbf + 2*1024*1024; off = i - HID4 - 2*W4; }
    float4 v = ((const float4*)src)[off];
    bf16x4 o = {(bf16_t)v.x, (bf16_t)v.y, (bf16_t)v.z, (bf16_t)v.w};
    ((bf16x4*)dst)[off] = o;
}

// ---------------------------------------------------------------------------
// Fused QKV projection — r8 config FROZEN (best measured: non-attn ~95 us).
// 128x64 tile, BK=64, GLL dbuf with counted vmcnt(6), lgkmcnt(0) before the
// trailing s_barrier (r12 race fix), XCD-chunked swizzle.
// r17: reg-staging is 10 us slower — keep GLL.  r7: 128x128/512thr is 8 us
// slower.  Non-attn is ~95 us across ALL proj variants (stall-bound).
// ---------------------------------------------------------------------------
__global__ __launch_bounds__(256) void proj_mfma_kernel(
        const bf16_t* __restrict__ Abf,   // [2048][1024]
        const bf16_t* __restrict__ Wbf,   // [3072][1024]  (Wq;Wk;Wv)
        const float* __restrict__ bq, const float* __restrict__ bk,
        const float* __restrict__ bv,
        bf16_t* __restrict__ Qbf, bf16_t* __restrict__ Kbf, bf16_t* __restrict__ Vt) {
    __shared__ __align__(16) char psmem[49152];   // buf b: As@b*24576, Bs@+16384
    bf16_t* Es = (bf16_t*)psmem;                  // epilogue staging (aliases buf0)

    const int tid = threadIdx.x;
    const int w = tid >> 6, l = tid & 63;

    // XCD-chunked bijective swizzle: hw id p runs on XCD p%8; XCD c gets the
    // contiguous logical range [96c, 96c+96).
    const int p = blockIdx.x;
    const int L = (p & 7) * 96 + (p >> 3);
    const int n0 = (L % 48) * 64;             // n-tile (48)
    const int m0 = (L / 48) * 128;            // m-panel (16)

    const int wm = w & 1, wn = w >> 1;
    const int frow = l & 15;
    const int kq = (l >> 4) * 8;

    f32x4 acc[4][2] = {};

    // stage tile kt into buffer buf (6 GLLs per thread: 4 A + 2 B)
    auto stage = [&](int buf, int kt) {
        char* As = psmem + buf * 24576;
        char* Bs = As + 16384;
#pragma unroll
        for (int t = 0; t < 4; t++) {          // A: 1024 16B-chunks
            int c = t * 256 + tid;
            int row = c >> 3, ce = (c & 7) * 8;
            GLL(Abf + (size_t)(m0 + row) * H_ + kt + ce, As + c * 16);
        }
#pragma unroll
        for (int t = 0; t < 2; t++) {          // B: 512 16B-chunks
            int c = t * 256 + tid;
            int row = c >> 3, ce = (c & 7) * 8;
            GLL(Wbf + (size_t)(n0 + row) * H_ + kt + ce, Bs + c * 16);
        }
    };

    stage(0, 0);
    for (int it = 0; it < 16; it++) {
        const int buf = it & 1;
        if (it < 15) {
            stage(buf ^ 1, (it + 1) * 64);     // issue next tile's loads first
            VMCNT(6);                          // wait only the CURRENT tile's 6
        } else {
            VMCNT(0);
        }
        BARRIER_RAW();                         // all threads' cur-tile GLLs landed
        const bf16_t* As = (const bf16_t*)(psmem + buf * 24576);
        const bf16_t* Bs = (const bf16_t*)(psmem + buf * 24576 + 16384);
#pragma unroll
        for (int h = 0; h < 2; h++) {
            bf16x8 af[4], bfr[2];
#pragma unroll
            for (int im = 0; im < 4; im++)
                af[im] = *(const bf16x8*)&As[(wm * 64 + im * 16 + frow) * 64 + h * 32 + kq];
#pragma unroll
            for (int in = 0; in < 2; in++)
                bfr[in] = *(const bf16x8*)&Bs[(wn * 32 + in * 16 + frow) * 64 + h * 32 + kq];
#pragma unroll
            for (int im = 0; im < 4; im++)
#pragma unroll
                for (int in = 0; in < 2; in++)
                    acc[im][in] = MFMA16(af[im], bfr[in], acc[im][in]);
        }
        LGKM_FENCE();                          // drain ds_reads BEFORE barrier (r12 race)
        BARRIER_RAW();                         // now safe to overwrite this buf
    }

    const int proj = n0 >> 10;
    const int cn = l & 15, cr4 = (l >> 4) * 4;
    const int bb = m0 >> 10, mrem = m0 & 1023;
    const int nn = (n0 & 1023) >> 6;           // head index (tile is 64-aligned)

    if (proj < 2) {
        const float* bias = proj == 0 ? bq : bk;
        bf16_t* bdst = proj == 0 ? Qbf : Kbf;
#pragma unroll
        for (int im = 0; im < 4; im++) {
#pragma unroll
            for (int in = 0; in < 2; in++) {
                int nl = wn * 32 + in * 16 + cn;
                float bsv = bias[(n0 & 1023) + nl];
                int ml = wm * 64 + im * 16 + cr4;
#pragma unroll
                for (int vr = 0; vr < 4; vr++)
                    Es[(ml + vr) * 72 + nl] = (bf16_t)(acc[im][in][vr] + bsv);
            }
        }
        __syncthreads();
        bf16_t* base = bdst + (size_t)(bb * NH_ + nn) * S_ * D_ + (size_t)mrem * D_;
#pragma unroll
        for (int t = 0; t < 4; t++) {
            int c = t * 256 + tid;             // 128 rows x 8 chunks
            int ml = c >> 3, c8 = (c & 7) * 8;
            *(bf16x8*)&base[(size_t)ml * D_ + c8] = *(const bf16x8*)&Es[ml * 72 + c8];
        }
    } else {
        bf16_t* EsV = Es;                      // [64 d][136 m-pad]
#pragma unroll
        for (int im = 0; im < 4; im++) {
#pragma unroll
            for (int in = 0; in < 2; in++) {
                int nl = wn * 32 + in * 16 + cn;   // dd
                float bsv = bv[(n0 & 1023) + nl];
                int ml = wm * 64 + im * 16 + cr4;
                bf16x4 pv = {(bf16_t)(acc[im][in][0] + bsv), (bf16_t)(acc[im][in][1] + bsv),
                             (bf16_t)(acc[im][in][2] + bsv), (bf16_t)(acc[im][in][3] + bsv)};
                *(bf16x4*)&EsV[nl * 136 + ml] = pv;
            }
        }
        __syncthreads();
        bf16_t* base = Vt + (size_t)(bb * NH_ + nn) * D_ * S_ + mrem;
#pragma unroll
        for (int t = 0; t < 4; t++) {
            int c = t * 256 + tid;             // 64 rows(d) x 16 chunks
            int dd = c >> 4, s8 = (c & 15) * 8;
            *(bf16x8*)&base[(size_t)dd * S_ + s8] = *(const bf16x8*)&EsV[dd * 136 + s8];
        }
    }
}

// ---------------------------------------------------------------------------
// MFMA attention — r19: r10's 2-q-tile body (64.8 us, VGPR 100, zero spill)
// + K software pipeline, the r4 mechanism that was blocked by the (256,4)
// 128-reg cap and is now affordable under (256,2) (~256 cap):
//  - next kt's K half1 + mask prefetched during transform+PV (~800 cy cover);
//  - K half2 issued BEFORE half1's MFMAs consume kfA.
// r10 evidence: ILP is the lever (dur fell 78->65 while occupancy fell
// 36%->19%).  This removes the last exposed K-latency (2x ~200cy per kt).
// Tripwires: WRITE_SIZE == 8192 KB exactly (spill -> revert to r10 body),
// VGPR <= 256.
// ---------------------------------------------------------------------------
__global__ __launch_bounds__(256, 2) void attn_mfma_kernel(
        const bf16_t* __restrict__ Qbf, const bf16_t* __restrict__ Kbf,
        const bf16_t* __restrict__ Vt,  const bf16_t* __restrict__ tab_bf,
        const bf16_t* __restrict__ tabT_bf, const float* __restrict__ tab,
        const float* __restrict__ mask, float* __restrict__ out) {
    // aliased region: loop phase = PlsA 4x32x72 bf16 (18432 B) + Qr 32x136
    // bf16 (8704 B) = 27136 B; epilogue phase = Osh 4x32x68 f32 (34816 B).
    __shared__ __align__(16) char reg0[34816];
    __shared__ __align__(16) bf16_t Pb[32 * QRSTR];       // 8.7 KB
    __shared__ float Ptail[32][2];                        // 0.26 KB
    __shared__ float SArr[4][32][3];                      // 1.5 KB

    bf16_t* PlsAall = (bf16_t*)reg0;                      // [4][32*PSTR]
    bf16_t* Qr = (bf16_t*)(reg0 + 18432);                 // [32*QRSTR]
    float (*Osh)[32][68] = (float (*)[32][68])reg0;       // epilogue alias

    const int tid = threadIdx.x;
    const int w = tid >> 6, l = tid & 63;
    const int lr = l & 15;
    const int lk = (l >> 4) * 8;
    const int reg4 = (l >> 4) * 4;

    const int gid = blockIdx.x;
    const int hl = gid & 31;            // same head -> same XCD (L2 locality)
    const int qpair = gid >> 5;         // 0..31
    const int b = hl >> 4, h = hl & 15;
    const int q0 = qpair * 32;          // tile0 = q0, tile1 = q0+16

    const size_t bh = (size_t)(b * NH_ + h);
    const bf16_t* Qh = Qbf + bh * S_ * D_;
    const bf16_t* Kh = Kbf + bh * S_ * D_;
    const bf16_t* Vh = Vt + bh * D_ * S_;
    const float* mrow = mask + b * S_;
    bf16_t* myP = PlsAall + w * 32 * PSTR;

    // zero Pb + Ptail
    for (int e = tid; e < 32 * QRSTR / 2; e += 256) ((unsigned*)Pb)[e] = 0u;
    if (tid < 32) { Ptail[tid][0] = 0.f; Ptail[tid][1] = 0.f; }

    // Q A-frags for both tiles (same addresses in all waves -> L1 hits)
    bf16x8 af0 = *(const bf16x8*)&Qh[(size_t)(q0 + lr) * D_ + lk];
    bf16x8 af1 = *(const bf16x8*)&Qh[(size_t)(q0 + lr) * D_ + 32 + lk];
    bf16x8 ag0 = *(const bf16x8*)&Qh[(size_t)(q0 + 16 + lr) * D_ + lk];
    bf16x8 ag1 = *(const bf16x8*)&Qh[(size_t)(q0 + 16 + lr) * D_ + 32 + lk];

    // Qr[i][r] = q_i . tab[r] for 32 rows, n-tiles split across waves
    for (int nt = w; nt < 9; nt += 4) {
        f32x4 qa = {0.f, 0.f, 0.f, 0.f};
        f32x4 qb = {0.f, 0.f, 0.f, 0.f};
        const bf16_t* tb = tab_bf + (size_t)(nt * 16 + lr) * D_;
        bf16x8 t0 = *(const bf16x8*)&tb[lk];
        bf16x8 t1 = *(const bf16x8*)&tb[32 + lk];
        qa = MFMA16(af0, t0, qa); qa = MFMA16(af1, t1, qa);
        qb = MFMA16(ag0, t0, qb); qb = MFMA16(ag1, t1, qb);
        int col = nt * 16 + lr;
        if (col <= 128) {
#pragma unroll
            for (int r = 0; r < 4; r++) {
                Qr[(reg4 + r) * QRSTR + col] = (bf16_t)qa[r];
                Qr[(16 + reg4 + r) * QRSTR + col] = (bf16_t)qb[r];
            }
        }
    }
    __syncthreads();

    float QrLo0[4], QrHi0[4], QrLo1[4], QrHi1[4];
#pragma unroll
    for (int r = 0; r < 4; r++) {
        QrLo0[r] = (float)Qr[(reg4 + r) * QRSTR + 0];
        QrHi0[r] = (float)Qr[(reg4 + r) * QRSTR + 128];
        QrLo1[r] = (float)Qr[(16 + reg4 + r) * QRSTR + 0];
        QrHi1[r] = (float)Qr[(16 + reg4 + r) * QRSTR + 128];
    }

    f32x4 oacc0[5] = {};  // tile0: 4 d-tiles + stats
    f32x4 oacc1[5] = {};  // tile1
    const int kbase = w * 256;

    // K software pipeline: kt=0's half1 + mask in flight before the loop
    bf16x8 kfA[4];
    float mjA[4];
#pragma unroll
    for (int nt = 0; nt < 4; nt++) {
        kfA[nt] = *(const bf16x8*)&Kh[(size_t)(kbase + nt * 16 + lr) * D_ + lk];
        mjA[nt] = mrow[kbase + nt * 16 + lr];
    }

    for (int kt = 0; kt < 4; kt++) {
        const int k0 = kbase + kt * 64;
        const int qa0 = q0, qa1 = q0 + 16;
        const bool allLo0 = (k0 + 63 - qa0 <= -64);
        const bool allHi0 = (k0 - (qa0 + 15) >= 64);
        const bool mixed0 = !(allLo0 || allHi0);
        const bool allLo1 = (k0 + 63 - qa1 <= -64);
        const bool allHi1 = (k0 - (qa1 + 15) >= 64);
        const bool mixed1 = !(allLo1 || allHi1);

        // snapshot prefetched mask before mjA is overwritten for next kt
        float mj[4];
#pragma unroll
        for (int nt = 0; nt < 4; nt++) mj[nt] = mjA[nt];

        // K half2 issued BEFORE half1's MFMAs consume kfA
        bf16x8 kfB[4];
#pragma unroll
        for (int nt = 0; nt < 4; nt++)
            kfB[nt] = *(const bf16x8*)&Kh[(size_t)(k0 + nt * 16 + lr) * D_ + 32 + lk];

        // S = Q K^T for both tiles; kfA already resident
        f32x4 sac0[4] = {}, sac1[4] = {};
#pragma unroll
        for (int nt = 0; nt < 4; nt++) sac0[nt] = MFMA16(af0, kfA[nt], sac0[nt]);
#pragma unroll
        for (int nt = 0; nt < 4; nt++) sac1[nt] = MFMA16(ag0, kfA[nt], sac1[nt]);
#pragma unroll
        for (int nt = 0; nt < 4; nt++) sac0[nt] = MFMA16(af1, kfB[nt], sac0[nt]);
#pragma unroll
        for (int nt = 0; nt < 4; nt++) sac1[nt] = MFMA16(ag1, kfB[nt], sac1[nt]);

        // prefetch V (shared by both tiles) before the transforms
        bf16x8 vf[8];
#pragma unroll
        for (int nt = 0; nt < 4; nt++) {
            const bf16_t* vb = Vh + (size_t)(nt * 16 + lr) * S_ + k0;
            vf[2 * nt]     = *(const bf16x8*)&vb[lk];
            vf[2 * nt + 1] = *(const bf16x8*)&vb[32 + lk];
        }

        // prefetch NEXT kt's K half1 + mask; lands during transform+PV
        if (kt < 3) {
            const int k1 = k0 + 64;
#pragma unroll
            for (int nt = 0; nt < 4; nt++) {
                kfA[nt] = *(const bf16x8*)&Kh[(size_t)(k1 + nt * 16 + lr) * D_ + lk];
                mjA[nt] = mrow[k1 + nt * 16 + lr];
            }
        }

        // transform tile0
#pragma unroll
        for (int nt = 0; nt < 4; nt++) {
            int gj = k0 + nt * 16 + lr;
#pragma unroll
            for (int r = 0; r < 4; r++) {
                int gi = qa0 + reg4 + r;
                float rel;
                if (allLo0) rel = QrLo0[r];
                else if (allHi0) rel = QrHi0[r];
                else {
                    int off = gj - gi;
                    off = off < -64 ? -64 : (off > 64 ? 64 : off);
                    rel = (float)Qr[(reg4 + r) * QRSTR + off + 64];
                }
                float p = __expf((sac0[nt][r] + rel) * 0.125f + mj[nt]);
                if (mixed0) {
                    int off = gj - gi;
                    if (off <= -64)      atomicAdd(&Ptail[reg4 + r][0], p);
                    else if (off >= 64)  atomicAdd(&Ptail[reg4 + r][1], p);
                    else                 Pb[(reg4 + r) * QRSTR + off + 64] = (bf16_t)p;
                }
                myP[(reg4 + r) * PSTR + nt * 16 + lr] = (bf16_t)p;
            }
        }
        // transform tile1
#pragma unroll
        for (int nt = 0; nt < 4; nt++) {
            int gj = k0 + nt * 16 + lr;
#pragma unroll
            for (int r = 0; r < 4; r++) {
                int gi = qa1 + reg4 + r;
                float rel;
                if (allLo1) rel = QrLo1[r];
                else if (allHi1) rel = QrHi1[r];
                else {
                    int off = gj - gi;
                    off = off < -64 ? -64 : (off > 64 ? 64 : off);
                    rel = (float)Qr[(16 + reg4 + r) * QRSTR + off + 64];
                }
                float p = __expf((sac1[nt][r] + rel) * 0.125f + mj[nt]);
                if (mixed1) {
                    int off = gj - gi;
                    if (off <= -64)      atomicAdd(&Ptail[16 + reg4 + r][0], p);
                    else if (off >= 64)  atomicAdd(&Ptail[16 + reg4 + r][1], p);
                    else                 Pb[(16 + reg4 + r) * QRSTR + off + 64] = (bf16_t)p;
                }
                myP[(16 + reg4 + r) * PSTR + nt * 16 + lr] = (bf16_t)p;
            }
        }
        LGKM_FENCE();

        float ov0 = (lr == 0) ? 1.f : (lr == 1) ? (allLo0 ? 1.f : 0.f)
                  : (lr == 2) ? (allHi0 ? 1.f : 0.f) : 0.f;
        float ov1 = (lr == 0) ? 1.f : (lr == 1) ? (allLo1 ? 1.f : 0.f)
                  : (lr == 2) ? (allHi1 ? 1.f : 0.f) : 0.f;
        bf16_t ob0 = (bf16_t)ov0, ob1 = (bf16_t)ov1;
        bf16x8 ones0 = {ob0, ob0, ob0, ob0, ob0, ob0, ob0, ob0};
        bf16x8 ones1 = {ob1, ob1, ob1, ob1, ob1, ob1, ob1, ob1};

        bf16x8 pa0 = *(const bf16x8*)&myP[lr * PSTR + lk];
        bf16x8 pa1 = *(const bf16x8*)&myP[lr * PSTR + 32 + lk];
        bf16x8 pb0 = *(const bf16x8*)&myP[(16 + lr) * PSTR + lk];
        bf16x8 pb1 = *(const bf16x8*)&myP[(16 + lr) * PSTR + 32 + lk];
#pragma unroll
        for (int nt = 0; nt < 4; nt++) {
            oacc0[nt] = MFMA16(pa0, vf[2 * nt], oacc0[nt]);
            oacc0[nt] = MFMA16(pa1, vf[2 * nt + 1], oacc0[nt]);
            oacc1[nt] = MFMA16(pb0, vf[2 * nt], oacc1[nt]);
            oacc1[nt] = MFMA16(pb1, vf[2 * nt + 1], oacc1[nt]);
        }
        oacc0[4] = MFMA16(pa0, ones0, oacc0[4]);
        oacc0[4] = MFMA16(pa1, ones0, oacc0[4]);
        oacc1[4] = MFMA16(pb0, ones1, oacc1[4]);
        oacc1[4] = MFMA16(pb1, ones1, oacc1[4]);
    }

    // all waves done reading myP/Qr before Osh overwrites the aliased region
    __syncthreads();

    // partials -> LDS for both tiles
    if (lr < 3) {
#pragma unroll
        for (int r = 0; r < 4; r++) {
            SArr[w][reg4 + r][lr] = oacc0[4][r];
            SArr[w][16 + reg4 + r][lr] = oacc1[4][r];
        }
    }
#pragma unroll
    for (int nt = 0; nt < 4; nt++)
#pragma unroll
        for (int r = 0; r < 4; r++) {
            Osh[w][reg4 + r][nt * 16 + lr] = oacc0[nt][r];
            Osh[w][16 + reg4 + r][nt * 16 + lr] = oacc1[nt][r];
        }
    __syncthreads();

    // wave w owns d-tile w for both q-tiles
#pragma unroll
    for (int t = 0; t < 2; t++) {
        f32x4 c = {};
#pragma unroll
        for (int r = 0; r < 4; r++) {
            int row = t * 16 + reg4 + r;
            c[r] = Osh[0][row][w * 16 + lr] + Osh[1][row][w * 16 + lr] +
                   Osh[2][row][w * 16 + lr] + Osh[3][row][w * 16 + lr];
        }
#pragma unroll
        for (int kc = 0; kc < 4; kc++) {
            bf16x8 pa = *(const bf16x8*)&Pb[(t * 16 + lr) * QRSTR + kc * 32 + lk];
            bf16x8 tb = *(const bf16x8*)&tabT_bf[(size_t)(w * 16 + lr) * 128 + kc * 32 + lk];
            c = MFMA16(pa, tb, c);
        }
#pragma unroll
        for (int r = 0; r < 4; r++) {
            int row = t * 16 + reg4 + r, gi = q0 + row;
            float ls  = SArr[0][row][0] + SArr[1][row][0] + SArr[2][row][0] + SArr[3][row][0];
            float plo = SArr[0][row][1] + SArr[1][row][1] + SArr[2][row][1] + SArr[3][row][1]
                      + Ptail[row][0];
            float phi = SArr[0][row][2] + SArr[1][row][2] + SArr[2][row][2] + SArr[3][row][2]
                      + Ptail[row][1];
            int d = w * 16 + lr;
            float o = c[r] + plo * tab[d] + phi * tab[128 * D_ + d];
            out[((size_t)(b * S_ + gi) * NH_ + h) * D_ + d] = o / ls;
        }
    }
}

// ---------------------------------------------------------------------------
extern "C" void kernel_launch(void* const* d_in, const int* in_sizes, int n_in,
                              void* d_out, int out_size, void* d_ws, size_t ws_size,
                              hipStream_t stream) {
    const float* hidden = (const float*)d_in[0];
    const float* mask   = (const float*)d_in[1];
    const float* Wq     = (const float*)d_in[2];
    const float* bq     = (const float*)d_in[3];
    const float* Wk     = (const float*)d_in[4];
    const float* bk     = (const float*)d_in[5];
    const float* Wv     = (const float*)d_in[6];
    const float* bv     = (const float*)d_in[7];
    float* out = (float*)d_out;

    char* wsb = (char*)d_ws;
    bf16_t* Qbf    = (bf16_t*)(wsb);                                // 4 MB
    bf16_t* Kbf    = (bf16_t*)(wsb + (4u << 20));                   // 4 MB
    bf16_t* Vt     = (bf16_t*)(wsb + (8u << 20));                   // 4 MB
    float*  tab    = (float*) (wsb + (12u << 20));                  // 33 KB
    bf16_t* tab_bf = (bf16_t*)(wsb + (12u << 20) + (64u << 10));    // 18.4 KB
    bf16_t* tabT   = (bf16_t*)(wsb + (12u << 20) + (96u << 10));    // 16 KB
    bf16_t* hidbf  = (bf16_t*)(wsb + (12u << 20) + (128u << 10));   // 4 MB
    bf16_t* wbf    = (bf16_t*)(wsb + (16u << 20) + (128u << 10));   // 6 MB

    cast_tab_kernel<<<dim3(5156), dim3(256), 0, stream>>>(
        hidden, Wq, Wk, Wv, hidbf, wbf, tab, tab_bf, tabT);

    proj_mfma_kernel<<<dim3(768), dim3(256), 0, stream>>>(
        hidbf, wbf, bq, bk, bv, Qbf, Kbf, Vt);

    attn_mfma_kernel<<<dim3((S_ / 16) * NH_ * B_ / 2), dim3(256), 0, stream>>>(
        Qbf, Kbf, Vt, tab_bf, tabT, tab, mask, out);
}

// Round 12
// 162.148 us; speedup vs baseline: 1.0081x; 1.0081x over previous
//
#include <hip/hip_runtime.h>
#include <hip/hip_bf16.h>
#include <math.h>

#define B_ 2
#define S_ 1024
#define H_ 1024
#define NH_ 16
#define D_ 64
#define VOCAB 129

#define PSTR 72     // P LDS row stride (bf16); 144 B rows, 16B-aligned bf16x8 reads
#define QRSTR 136   // Qr/Pb LDS row stride (bf16); 272 B rows, 16B-aligned
#define OSTR 17     // OshF f32 inner stride (rows 4 apart -> 4*17%32=4, conflict-free)

typedef __bf16 bf16_t;
typedef __bf16 bf16x8 __attribute__((ext_vector_type(8)));
typedef __bf16 bf16x4 __attribute__((ext_vector_type(4)));
typedef float f32x4 __attribute__((ext_vector_type(4)));

#define MFMA16(a, b, c) __builtin_amdgcn_mfma_f32_16x16x32_bf16(a, b, c, 0, 0, 0)
#define LGKM_FENCE() __asm__ volatile("s_waitcnt lgkmcnt(0)" ::: "memory")
#define BARRIER_RAW() __asm__ volatile("s_barrier" ::: "memory")
#define VMCNT(n) __asm__ volatile("s_waitcnt vmcnt(" #n ")" ::: "memory")
#define GLL(gp, lp) __builtin_amdgcn_global_load_lds( \
    (const __attribute__((address_space(1))) void*)(gp), \
    (__attribute__((address_space(3))) void*)(lp), 16, 0, 0)

// ---------------------------------------------------------------------------
// Fused: blocks [0,5120) cast hidden/Wq/Wk/Wv f32->bf16; blocks [5120,5156)
// build the sinusoid tables.  (r17 lesson: fusing the cast INTO proj via
// reg-staging lost 10 us — GLL direct-to-LDS is mandatory for proj.)
// ---------------------------------------------------------------------------
__global__ __launch_bounds__(256) void cast_tab_kernel(
        const float* __restrict__ hidden, const float* __restrict__ Wq,
        const float* __restrict__ Wk, const float* __restrict__ Wv,
        bf16_t* __restrict__ hidbf, bf16_t* __restrict__ wbf,
        float* __restrict__ tab, bf16_t* __restrict__ tab_bf,
        bf16_t* __restrict__ tabT_bf) {
    const int bid = blockIdx.x;
    const int tid = threadIdx.x;
    if (bid >= 5120) {
        int r = (bid - 5120) * 4 + (tid >> 6);   // 0..143
        int d = tid & 63;
        float val = 0.f;
        if (r < VOCAB) {
            int p = d >> 1;
            float div = __expf((float)(2 * p) * (-logf(10000.0f) / (float)D_));
            float ang = (float)r * div;
            val = (d & 1) ? cosf(ang) : sinf(ang);
            tab[r * D_ + d] = val;
        }
        tab_bf[r * D_ + d] = (bf16_t)val;
        if (r < 128) tabT_bf[d * 128 + r] = (bf16_t)val;
        return;
    }
    const int i = bid * 256 + tid;   // float4 index, < 1280K
    const int HID4 = 512 * 1024, W4 = 256 * 1024;
    const float* src;
    bf16_t* dst;
    int off;
    if (i < HID4)            { src = hidden; dst = hidbf;             off = i; }
    else if (i < HID4 + W4)  { src = Wq;     dst = wbf;               off = i - HID4; }
    else if (i < HID4 + 2*W4){ src = Wk;     dst = wbf + 1024*1024;   off = i - HID4 - W4; }
    else                     { src = Wv;     dst = wbf + 2*1024*1024; off = i - HID4 - 2*W4; }
    float4 v = ((const float4*)src)[off];
    bf16x4 o = {(bf16_t)v.x, (bf16_t)v.y, (bf16_t)v.z, (bf16_t)v.w};
    ((bf16x4*)dst)[off] = o;
}

// ---------------------------------------------------------------------------
// Fused QKV projection — r8 config FROZEN (best measured: non-attn ~95 us).
// 128x64 tile, BK=64, GLL dbuf with counted vmcnt(6), lgkmcnt(0) before the
// trailing s_barrier (r12 race fix), XCD-chunked swizzle.
// r17: reg-staging is 10 us slower — keep GLL.  r7: 128x128/512thr is 8 us
// slower.  Non-attn is ~95 us across ALL proj variants (stall-bound).
// ---------------------------------------------------------------------------
__global__ __launch_bounds__(256) void proj_mfma_kernel(
        const bf16_t* __restrict__ Abf,   // [2048][1024]
        const bf16_t* __restrict__ Wbf,   // [3072][1024]  (Wq;Wk;Wv)
        const float* __restrict__ bq, const float* __restrict__ bk,
        const float* __restrict__ bv,
        bf16_t* __restrict__ Qbf, bf16_t* __restrict__ Kbf, bf16_t* __restrict__ Vt) {
    __shared__ __align__(16) char psmem[49152];   // buf b: As@b*24576, Bs@+16384
    bf16_t* Es = (bf16_t*)psmem;                  // epilogue staging (aliases buf0)

    const int tid = threadIdx.x;
    const int w = tid >> 6, l = tid & 63;

    // XCD-chunked bijective swizzle: hw id p runs on XCD p%8; XCD c gets the
    // contiguous logical range [96c, 96c+96).
    const int p = blockIdx.x;
    const int L = (p & 7) * 96 + (p >> 3);
    const int n0 = (L % 48) * 64;             // n-tile (48)
    const int m0 = (L / 48) * 128;            // m-panel (16)

    const int wm = w & 1, wn = w >> 1;
    const int frow = l & 15;
    const int kq = (l >> 4) * 8;

    f32x4 acc[4][2] = {};

    // stage tile kt into buffer buf (6 GLLs per thread: 4 A + 2 B)
    auto stage = [&](int buf, int kt) {
        char* As = psmem + buf * 24576;
        char* Bs = As + 16384;
#pragma unroll
        for (int t = 0; t < 4; t++) {          // A: 1024 16B-chunks
            int c = t * 256 + tid;
            int row = c >> 3, ce = (c & 7) * 8;
            GLL(Abf + (size_t)(m0 + row) * H_ + kt + ce, As + c * 16);
        }
#pragma unroll
        for (int t = 0; t < 2; t++) {          // B: 512 16B-chunks
            int c = t * 256 + tid;
            int row = c >> 3, ce = (c & 7) * 8;
            GLL(Wbf + (size_t)(n0 + row) * H_ + kt + ce, Bs + c * 16);
        }
    };

    stage(0, 0);
    for (int it = 0; it < 16; it++) {
        const int buf = it & 1;
        if (it < 15) {
            stage(buf ^ 1, (it + 1) * 64);     // issue next tile's loads first
            VMCNT(6);                          // wait only the CURRENT tile's 6
        } else {
            VMCNT(0);
        }
        BARRIER_RAW();                         // all threads' cur-tile GLLs landed
        const bf16_t* As = (const bf16_t*)(psmem + buf * 24576);
        const bf16_t* Bs = (const bf16_t*)(psmem + buf * 24576 + 16384);
#pragma unroll
        for (int h = 0; h < 2; h++) {
            bf16x8 af[4], bfr[2];
#pragma unroll
            for (int im = 0; im < 4; im++)
                af[im] = *(const bf16x8*)&As[(wm * 64 + im * 16 + frow) * 64 + h * 32 + kq];
#pragma unroll
            for (int in = 0; in < 2; in++)
                bfr[in] = *(const bf16x8*)&Bs[(wn * 32 + in * 16 + frow) * 64 + h * 32 + kq];
#pragma unroll
            for (int im = 0; im < 4; im++)
#pragma unroll
                for (int in = 0; in < 2; in++)
                    acc[im][in] = MFMA16(af[im], bfr[in], acc[im][in]);
        }
        LGKM_FENCE();                          // drain ds_reads BEFORE barrier (r12 race)
        BARRIER_RAW();                         // now safe to overwrite this buf
    }

    const int proj = n0 >> 10;
    const int cn = l & 15, cr4 = (l >> 4) * 4;
    const int bb = m0 >> 10, mrem = m0 & 1023;
    const int nn = (n0 & 1023) >> 6;           // head index (tile is 64-aligned)

    if (proj < 2) {
        const float* bias = proj == 0 ? bq : bk;
        bf16_t* bdst = proj == 0 ? Qbf : Kbf;
#pragma unroll
        for (int im = 0; im < 4; im++) {
#pragma unroll
            for (int in = 0; in < 2; in++) {
                int nl = wn * 32 + in * 16 + cn;
                float bsv = bias[(n0 & 1023) + nl];
                int ml = wm * 64 + im * 16 + cr4;
#pragma unroll
                for (int vr = 0; vr < 4; vr++)
                    Es[(ml + vr) * 72 + nl] = (bf16_t)(acc[im][in][vr] + bsv);
            }
        }
        __syncthreads();
        bf16_t* base = bdst + (size_t)(bb * NH_ + nn) * S_ * D_ + (size_t)mrem * D_;
#pragma unroll
        for (int t = 0; t < 4; t++) {
            int c = t * 256 + tid;             // 128 rows x 8 chunks
            int ml = c >> 3, c8 = (c & 7) * 8;
            *(bf16x8*)&base[(size_t)ml * D_ + c8] = *(const bf16x8*)&Es[ml * 72 + c8];
        }
    } else {
        bf16_t* EsV = Es;                      // [64 d][136 m-pad]
#pragma unroll
        for (int im = 0; im < 4; im++) {
#pragma unroll
            for (int in = 0; in < 2; in++) {
                int nl = wn * 32 + in * 16 + cn;   // dd
                float bsv = bv[(n0 & 1023) + nl];
                int ml = wm * 64 + im * 16 + cr4;
                bf16x4 pv = {(bf16_t)(acc[im][in][0] + bsv), (bf16_t)(acc[im][in][1] + bsv),
                             (bf16_t)(acc[im][in][2] + bsv), (bf16_t)(acc[im][in][3] + bsv)};
                *(bf16x4*)&EsV[nl * 136 + ml] = pv;
            }
        }
        __syncthreads();
        bf16_t* base = Vt + (size_t)(bb * NH_ + nn) * D_ * S_ + mrem;
#pragma unroll
        for (int t = 0; t < 4; t++) {
            int c = t * 256 + tid;             // 64 rows(d) x 16 chunks
            int dd = c >> 4, s8 = (c & 15) * 8;
            *(bf16x8*)&base[(size_t)dd * S_ + s8] = *(const bf16x8*)&EsV[dd * 136 + s8];
        }
    }
}

// ---------------------------------------------------------------------------
// MFMA attention — r20: r10's 2-q-tile body (64.8 us, VGPR 100) with the LDS
// footprint cut below 40 KB so 4 blocks/CU fit.  Evidence: grid 1024 = exactly
// 4 blocks/CU of work, but LDS 45.5 KB allowed only 3 -> a ragged 3+1 round
// schedule (measured occupancy 18.9% vs 37.5% possible).  VGPR 100 permits
// 5 waves/SIMD, so LDS is now the BINDING resource (unlike r11-1, when VGPR
// was).  Cut: each wave publishes only the 3 d-tiles it does NOT own
// (OshF[12][32][17] f32 = 25.5 KB aliasing loop-phase PlsA+Qr 26.5 KB; own
// tile stays in regs — pattern verified correct in r1's passing run).
// New LDS = 37632 B -> 4 blocks/CU, single full-resident round.
// r19 lesson: K-prefetch null (latency already hidden by dual-stream ILP) —
// reverted.  Loop code byte-identical to r10.
// Tripwires: VGPR <= 128 (4 waves/SIMD), WRITE_SIZE == 8192 KB exactly.
// ---------------------------------------------------------------------------
__global__ __launch_bounds__(256, 2) void attn_mfma_kernel(
        const bf16_t* __restrict__ Qbf, const bf16_t* __restrict__ Kbf,
        const bf16_t* __restrict__ Vt,  const bf16_t* __restrict__ tab_bf,
        const bf16_t* __restrict__ tabT_bf, const float* __restrict__ tab,
        const float* __restrict__ mask, float* __restrict__ out) {
    // aliased region: loop phase = PlsA 4x32x72 bf16 (18432 B) + Qr 32x136
    // bf16 (8704 B) = 27136 B; epilogue phase = OshF 12x32x17 f32 (26112 B).
    __shared__ __align__(16) char reg0[27136];
    __shared__ __align__(16) bf16_t Pb[32 * QRSTR];       // 8.7 KB
    __shared__ float Ptail[32][2];                        // 0.26 KB
    __shared__ float SArr[4][32][3];                      // 1.5 KB

    bf16_t* PlsAall = (bf16_t*)reg0;                      // [4][32*PSTR]
    bf16_t* Qr = (bf16_t*)(reg0 + 18432);                 // [32*QRSTR]
    float* OshF = (float*)reg0;                           // epilogue alias

    const int tid = threadIdx.x;
    const int w = tid >> 6, l = tid & 63;
    const int lr = l & 15;
    const int lk = (l >> 4) * 8;
    const int reg4 = (l >> 4) * 4;

    const int gid = blockIdx.x;
    const int hl = gid & 31;            // same head -> same XCD (L2 locality)
    const int qpair = gid >> 5;         // 0..31
    const int b = hl >> 4, h = hl & 15;
    const int q0 = qpair * 32;          // tile0 = q0, tile1 = q0+16

    const size_t bh = (size_t)(b * NH_ + h);
    const bf16_t* Qh = Qbf + bh * S_ * D_;
    const bf16_t* Kh = Kbf + bh * S_ * D_;
    const bf16_t* Vh = Vt + bh * D_ * S_;
    const float* mrow = mask + b * S_;
    bf16_t* myP = PlsAall + w * 32 * PSTR;

    // zero Pb + Ptail
    for (int e = tid; e < 32 * QRSTR / 2; e += 256) ((unsigned*)Pb)[e] = 0u;
    if (tid < 32) { Ptail[tid][0] = 0.f; Ptail[tid][1] = 0.f; }

    // Q A-frags for both tiles (same addresses in all waves -> L1 hits)
    bf16x8 af0 = *(const bf16x8*)&Qh[(size_t)(q0 + lr) * D_ + lk];
    bf16x8 af1 = *(const bf16x8*)&Qh[(size_t)(q0 + lr) * D_ + 32 + lk];
    bf16x8 ag0 = *(const bf16x8*)&Qh[(size_t)(q0 + 16 + lr) * D_ + lk];
    bf16x8 ag1 = *(const bf16x8*)&Qh[(size_t)(q0 + 16 + lr) * D_ + 32 + lk];

    // Qr[i][r] = q_i . tab[r] for 32 rows, n-tiles split across waves
    for (int nt = w; nt < 9; nt += 4) {
        f32x4 qa = {0.f, 0.f, 0.f, 0.f};
        f32x4 qb = {0.f, 0.f, 0.f, 0.f};
        const bf16_t* tb = tab_bf + (size_t)(nt * 16 + lr) * D_;
        bf16x8 t0 = *(const bf16x8*)&tb[lk];
        bf16x8 t1 = *(const bf16x8*)&tb[32 + lk];
        qa = MFMA16(af0, t0, qa); qa = MFMA16(af1, t1, qa);
        qb = MFMA16(ag0, t0, qb); qb = MFMA16(ag1, t1, qb);
        int col = nt * 16 + lr;
        if (col <= 128) {
#pragma unroll
            for (int r = 0; r < 4; r++) {
                Qr[(reg4 + r) * QRSTR + col] = (bf16_t)qa[r];
                Qr[(16 + reg4 + r) * QRSTR + col] = (bf16_t)qb[r];
            }
        }
    }
    __syncthreads();

    float QrLo0[4], QrHi0[4], QrLo1[4], QrHi1[4];
#pragma unroll
    for (int r = 0; r < 4; r++) {
        QrLo0[r] = (float)Qr[(reg4 + r) * QRSTR + 0];
        QrHi0[r] = (float)Qr[(reg4 + r) * QRSTR + 128];
        QrLo1[r] = (float)Qr[(16 + reg4 + r) * QRSTR + 0];
        QrHi1[r] = (float)Qr[(16 + reg4 + r) * QRSTR + 128];
    }

    f32x4 oacc0[5] = {};  // tile0: 4 d-tiles + stats
    f32x4 oacc1[5] = {};  // tile1
    const int kbase = w * 256;

    for (int kt = 0; kt < 4; kt++) {
        const int k0 = kbase + kt * 64;
        const int qa0 = q0, qa1 = q0 + 16;
        const bool allLo0 = (k0 + 63 - qa0 <= -64);
        const bool allHi0 = (k0 - (qa0 + 15) >= 64);
        const bool mixed0 = !(allLo0 || allHi0);
        const bool allLo1 = (k0 + 63 - qa1 <= -64);
        const bool allHi1 = (k0 - (qa1 + 15) >= 64);
        const bool mixed1 = !(allLo1 || allHi1);

        // mask (shared by both tiles)
        float mj[4];
#pragma unroll
        for (int nt = 0; nt < 4; nt++) mj[nt] = mrow[k0 + nt * 16 + lr];

        // S = Q K^T for both tiles; K-frags loaded ONCE
        f32x4 sac0[4] = {}, sac1[4] = {};
        {
            bf16x8 kf[4];
#pragma unroll
            for (int nt = 0; nt < 4; nt++)
                kf[nt] = *(const bf16x8*)&Kh[(size_t)(k0 + nt * 16 + lr) * D_ + lk];
#pragma unroll
            for (int nt = 0; nt < 4; nt++) sac0[nt] = MFMA16(af0, kf[nt], sac0[nt]);
#pragma unroll
            for (int nt = 0; nt < 4; nt++) sac1[nt] = MFMA16(ag0, kf[nt], sac1[nt]);
#pragma unroll
            for (int nt = 0; nt < 4; nt++)
                kf[nt] = *(const bf16x8*)&Kh[(size_t)(k0 + nt * 16 + lr) * D_ + 32 + lk];
#pragma unroll
            for (int nt = 0; nt < 4; nt++) sac0[nt] = MFMA16(af1, kf[nt], sac0[nt]);
#pragma unroll
            for (int nt = 0; nt < 4; nt++) sac1[nt] = MFMA16(ag1, kf[nt], sac1[nt]);
        }

        // prefetch V (shared by both tiles) before the transforms
        bf16x8 vf[8];
#pragma unroll
        for (int nt = 0; nt < 4; nt++) {
            const bf16_t* vb = Vh + (size_t)(nt * 16 + lr) * S_ + k0;
            vf[2 * nt]     = *(const bf16x8*)&vb[lk];
            vf[2 * nt + 1] = *(const bf16x8*)&vb[32 + lk];
        }

        // transform tile0
#pragma unroll
        for (int nt = 0; nt < 4; nt++) {
            int gj = k0 + nt * 16 + lr;
#pragma unroll
            for (int r = 0; r < 4; r++) {
                int gi = qa0 + reg4 + r;
                float rel;
                if (allLo0) rel = QrLo0[r];
                else if (allHi0) rel = QrHi0[r];
                else {
                    int off = gj - gi;
                    off = off < -64 ? -64 : (off > 64 ? 64 : off);
                    rel = (float)Qr[(reg4 + r) * QRSTR + off + 64];
                }
                float p = __expf((sac0[nt][r] + rel) * 0.125f + mj[nt]);
                if (mixed0) {
                    int off = gj - gi;
                    if (off <= -64)      atomicAdd(&Ptail[reg4 + r][0], p);
                    else if (off >= 64)  atomicAdd(&Ptail[reg4 + r][1], p);
                    else                 Pb[(reg4 + r) * QRSTR + off + 64] = (bf16_t)p;
                }
                myP[(reg4 + r) * PSTR + nt * 16 + lr] = (bf16_t)p;
            }
        }
        // transform tile1
#pragma unroll
        for (int nt = 0; nt < 4; nt++) {
            int gj = k0 + nt * 16 + lr;
#pragma unroll
            for (int r = 0; r < 4; r++) {
                int gi = qa1 + reg4 + r;
                float rel;
                if (allLo1) rel = QrLo1[r];
                else if (allHi1) rel = QrHi1[r];
                else {
                    int off = gj - gi;
                    off = off < -64 ? -64 : (off > 64 ? 64 : off);
                    rel = (float)Qr[(16 + reg4 + r) * QRSTR + off + 64];
                }
                float p = __expf((sac1[nt][r] + rel) * 0.125f + mj[nt]);
                if (mixed1) {
                    int off = gj - gi;
                    if (off <= -64)      atomicAdd(&Ptail[16 + reg4 + r][0], p);
                    else if (off >= 64)  atomicAdd(&Ptail[16 + reg4 + r][1], p);
                    else                 Pb[(16 + reg4 + r) * QRSTR + off + 64] = (bf16_t)p;
                }
                myP[(16 + reg4 + r) * PSTR + nt * 16 + lr] = (bf16_t)p;
            }
        }
        LGKM_FENCE();

        float ov0 = (lr == 0) ? 1.f : (lr == 1) ? (allLo0 ? 1.f : 0.f)
                  : (lr == 2) ? (allHi0 ? 1.f : 0.f) : 0.f;
        float ov1 = (lr == 0) ? 1.f : (lr == 1) ? (allLo1 ? 1.f : 0.f)
                  : (lr == 2) ? (allHi1 ? 1.f : 0.f) : 0.f;
        bf16_t ob0 = (bf16_t)ov0, ob1 = (bf16_t)ov1;
        bf16x8 ones0 = {ob0, ob0, ob0, ob0, ob0, ob0, ob0, ob0};
        bf16x8 ones1 = {ob1, ob1, ob1, ob1, ob1, ob1, ob1, ob1};

        bf16x8 pa0 = *(const bf16x8*)&myP[lr * PSTR + lk];
        bf16x8 pa1 = *(const bf16x8*)&myP[lr * PSTR + 32 + lk];
        bf16x8 pb0 = *(const bf16x8*)&myP[(16 + lr) * PSTR + lk];
        bf16x8 pb1 = *(const bf16x8*)&myP[(16 + lr) * PSTR + 32 + lk];
#pragma unroll
        for (int nt = 0; nt < 4; nt++) {
            oacc0[nt] = MFMA16(pa0, vf[2 * nt], oacc0[nt]);
            oacc0[nt] = MFMA16(pa1, vf[2 * nt + 1], oacc0[nt]);
            oacc1[nt] = MFMA16(pb0, vf[2 * nt], oacc1[nt]);
            oacc1[nt] = MFMA16(pb1, vf[2 * nt + 1], oacc1[nt]);
        }
        oacc0[4] = MFMA16(pa0, ones0, oacc0[4]);
        oacc0[4] = MFMA16(pa1, ones0, oacc0[4]);
        oacc1[4] = MFMA16(pb0, ones1, oacc1[4]);
        oacc1[4] = MFMA16(pb1, ones1, oacc1[4]);
    }

    // all waves done reading myP/Qr before OshF overwrites the aliased region
    __syncthreads();

    // partials: stats + the 3 d-tiles this wave does NOT own (own stays in
    // regs).  Writer w's 3 slots are disjoint per wave.
    if (lr < 3) {
#pragma unroll
        for (int r = 0; r < 4; r++) {
            SArr[w][reg4 + r][lr] = oacc0[4][r];
            SArr[w][16 + reg4 + r][lr] = oacc1[4][r];
        }
    }
    float ownv0[4] = {}, ownv1[4] = {};
#pragma unroll
    for (int nt = 0; nt < 4; nt++) {
        if (nt == w) {
#pragma unroll
            for (int r = 0; r < 4; r++) { ownv0[r] = oacc0[nt][r]; ownv1[r] = oacc1[nt][r]; }
        } else {
            int slot = nt - (nt > w ? 1 : 0);
#pragma unroll
            for (int r = 0; r < 4; r++) {
                OshF[((w * 3 + slot) * 32 + reg4 + r) * OSTR + lr] = oacc0[nt][r];
                OshF[((w * 3 + slot) * 32 + 16 + reg4 + r) * OSTR + lr] = oacc1[nt][r];
            }
        }
    }
    __syncthreads();

    // wave w owns d-tile w for both q-tiles: own regs + 3 published partials
#pragma unroll
    for (int t = 0; t < 2; t++) {
        f32x4 c = {};
#pragma unroll
        for (int r = 0; r < 4; r++) c[r] = (t == 0) ? ownv0[r] : ownv1[r];
#pragma unroll
        for (int w2 = 0; w2 < 4; w2++) {
            if (w2 != w) {
                int slot = w - (w > w2 ? 1 : 0);
#pragma unroll
                for (int r = 0; r < 4; r++)
                    c[r] += OshF[((w2 * 3 + slot) * 32 + t * 16 + reg4 + r) * OSTR + lr];
            }
        }
#pragma unroll
        for (int kc = 0; kc < 4; kc++) {
            bf16x8 pa = *(const bf16x8*)&Pb[(t * 16 + lr) * QRSTR + kc * 32 + lk];
            bf16x8 tb = *(const bf16x8*)&tabT_bf[(size_t)(w * 16 + lr) * 128 + kc * 32 + lk];
            c = MFMA16(pa, tb, c);
        }
#pragma unroll
        for (int r = 0; r < 4; r++) {
            int row = t * 16 + reg4 + r, gi = q0 + row;
            float ls  = SArr[0][row][0] + SArr[1][row][0] + SArr[2][row][0] + SArr[3][row][0];
            float plo = SArr[0][row][1] + SArr[1][row][1] + SArr[2][row][1] + SArr[3][row][1]
                      + Ptail[row][0];
            float phi = SArr[0][row][2] + SArr[1][row][2] + SArr[2][row][2] + SArr[3][row][2]
                      + Ptail[row][1];
            int d = w * 16 + lr;
            float o = c[r] + plo * tab[d] + phi * tab[128 * D_ + d];
            out[((size_t)(b * S_ + gi) * NH_ + h) * D_ + d] = o / ls;
        }
    }
}

// ---------------------------------------------------------------------------
extern "C" void kernel_launch(void* const* d_in, const int* in_sizes, int n_in,
                              void* d_out, int out_size, void* d_ws, size_t ws_size,
                              hipStream_t stream) {
    const float* hidden = (const float*)d_in[0];
    const float* mask   = (const float*)d_in[1];
    const float* Wq     = (const float*)d_in[2];
    const float* bq     = (const float*)d_in[3];
    const float* Wk     = (const float*)d_in[4];
    const float* bk     = (const float*)d_in[5];
    const float* Wv     = (const float*)d_in[6];
    const float* bv     = (const float*)d_in[7];
    float* out = (float*)d_out;

    char* wsb = (char*)d_ws;
    bf16_t* Qbf    = (bf16_t*)(wsb);                                // 4 MB
    bf16_t* Kbf    = (bf16_t*)(wsb + (4u << 20));                   // 4 MB
    bf16_t* Vt     = (bf16_t*)(wsb + (8u << 20));                   // 4 MB
    float*  tab    = (float*) (wsb + (12u << 20));                  // 33 KB
    bf16_t* tab_bf = (bf16_t*)(wsb + (12u << 20) + (64u << 10));    // 18.4 KB
    bf16_t* tabT   = (bf16_t*)(wsb + (12u << 20) + (96u << 10));    // 16 KB
    bf16_t* hidbf  = (bf16_t*)(wsb + (12u << 20) + (128u << 10));   // 4 MB
    bf16_t* wbf    = (bf16_t*)(wsb + (16u << 20) + (128u << 10));   // 6 MB

    cast_tab_kernel<<<dim3(5156), dim3(256), 0, stream>>>(
        hidden, Wq, Wk, Wv, hidbf, wbf, tab, tab_bf, tabT);

    proj_mfma_kernel<<<dim3(768), dim3(256), 0, stream>>>(
        hidbf, wbf, bq, bk, bv, Qbf, Kbf, Vt);

    attn_mfma_kernel<<<dim3((S_ / 16) * NH_ * B_ / 2), dim3(256), 0, stream>>>(
        Qbf, Kbf, Vt, tab_bf, tabT, tab, mask, out);
}

// Round 13
// 160.214 us; speedup vs baseline: 1.0203x; 1.0121x over previous
//
#include <hip/hip_runtime.h>
#include <hip/hip_bf16.h>
#include <math.h>

#define B_ 2
#define S_ 1024
#define H_ 1024
#define NH_ 16
#define D_ 64
#define VOCAB 129

#define PSTR 72     // P LDS row stride (bf16); 144 B rows, 16B-aligned bf16x8 reads
#define QRSTR 136   // Qr/Pb LDS row stride (bf16); 272 B rows, 16B-aligned
#define OSTR 17     // OshF f32 inner stride

typedef __bf16 bf16_t;
typedef __bf16 bf16x8 __attribute__((ext_vector_type(8)));
typedef __bf16 bf16x4 __attribute__((ext_vector_type(4)));
typedef float f32x4 __attribute__((ext_vector_type(4)));

#define MFMA16(a, b, c) __builtin_amdgcn_mfma_f32_16x16x32_bf16(a, b, c, 0, 0, 0)
#define LGKM_FENCE() __asm__ volatile("s_waitcnt lgkmcnt(0)" ::: "memory")
#define BARRIER_RAW() __asm__ volatile("s_barrier" ::: "memory")
#define VMCNT(n) __asm__ volatile("s_waitcnt vmcnt(" #n ")" ::: "memory")
#define GLL(gp, lp) __builtin_amdgcn_global_load_lds( \
    (const __attribute__((address_space(1))) void*)(gp), \
    (__attribute__((address_space(3))) void*)(lp), 16, 0, 0)

// ---------------------------------------------------------------------------
// Fused: blocks [0,5120) cast hidden/Wq/Wk/Wv f32->bf16; blocks [5120,5156)
// build the sinusoid tables.  (r17 lesson: fusing the cast INTO proj via
// reg-staging lost 10 us — GLL direct-to-LDS is mandatory for proj.)
// ---------------------------------------------------------------------------
__global__ __launch_bounds__(256) void cast_tab_kernel(
        const float* __restrict__ hidden, const float* __restrict__ Wq,
        const float* __restrict__ Wk, const float* __restrict__ Wv,
        bf16_t* __restrict__ hidbf, bf16_t* __restrict__ wbf,
        float* __restrict__ tab, bf16_t* __restrict__ tab_bf,
        bf16_t* __restrict__ tabT_bf) {
    const int bid = blockIdx.x;
    const int tid = threadIdx.x;
    if (bid >= 5120) {
        int r = (bid - 5120) * 4 + (tid >> 6);   // 0..143
        int d = tid & 63;
        float val = 0.f;
        if (r < VOCAB) {
            int p = d >> 1;
            float div = __expf((float)(2 * p) * (-logf(10000.0f) / (float)D_));
            float ang = (float)r * div;
            val = (d & 1) ? cosf(ang) : sinf(ang);
            tab[r * D_ + d] = val;
        }
        tab_bf[r * D_ + d] = (bf16_t)val;
        if (r < 128) tabT_bf[d * 128 + r] = (bf16_t)val;
        return;
    }
    const int i = bid * 256 + tid;   // float4 index, < 1280K
    const int HID4 = 512 * 1024, W4 = 256 * 1024;
    const float* src;
    bf16_t* dst;
    int off;
    if (i < HID4)            { src = hidden; dst = hidbf;             off = i; }
    else if (i < HID4 + W4)  { src = Wq;     dst = wbf;               off = i - HID4; }
    else if (i < HID4 + 2*W4){ src = Wk;     dst = wbf + 1024*1024;   off = i - HID4 - W4; }
    else                     { src = Wv;     dst = wbf + 2*1024*1024; off = i - HID4 - 2*W4; }
    float4 v = ((const float4*)src)[off];
    bf16x4 o = {(bf16_t)v.x, (bf16_t)v.y, (bf16_t)v.z, (bf16_t)v.w};
    ((bf16x4*)dst)[off] = o;
}

// ---------------------------------------------------------------------------
// Fused QKV projection — r8 config FROZEN (best measured: non-attn ~95 us).
// 128x64 tile, BK=64, GLL dbuf with counted vmcnt(6), lgkmcnt(0) before the
// trailing s_barrier (r12 race fix), XCD-chunked swizzle.
// r17: reg-staging is 10 us slower — keep GLL.  r7: 128x128/512thr is 8 us
// slower.  Non-attn is ~95 us across ALL proj variants (stall-bound).
// ---------------------------------------------------------------------------
__global__ __launch_bounds__(256) void proj_mfma_kernel(
        const bf16_t* __restrict__ Abf,   // [2048][1024]
        const bf16_t* __restrict__ Wbf,   // [3072][1024]  (Wq;Wk;Wv)
        const float* __restrict__ bq, const float* __restrict__ bk,
        const float* __restrict__ bv,
        bf16_t* __restrict__ Qbf, bf16_t* __restrict__ Kbf, bf16_t* __restrict__ Vt) {
    __shared__ __align__(16) char psmem[49152];   // buf b: As@b*24576, Bs@+16384
    bf16_t* Es = (bf16_t*)psmem;                  // epilogue staging (aliases buf0)

    const int tid = threadIdx.x;
    const int w = tid >> 6, l = tid & 63;

    const int p = blockIdx.x;
    const int L = (p & 7) * 96 + (p >> 3);
    const int n0 = (L % 48) * 64;             // n-tile (48)
    const int m0 = (L / 48) * 128;            // m-panel (16)

    const int wm = w & 1, wn = w >> 1;
    const int frow = l & 15;
    const int kq = (l >> 4) * 8;

    f32x4 acc[4][2] = {};

    auto stage = [&](int buf, int kt) {
        char* As = psmem + buf * 24576;
        char* Bs = As + 16384;
#pragma unroll
        for (int t = 0; t < 4; t++) {          // A: 1024 16B-chunks
            int c = t * 256 + tid;
            int row = c >> 3, ce = (c & 7) * 8;
            GLL(Abf + (size_t)(m0 + row) * H_ + kt + ce, As + c * 16);
        }
#pragma unroll
        for (int t = 0; t < 2; t++) {          // B: 512 16B-chunks
            int c = t * 256 + tid;
            int row = c >> 3, ce = (c & 7) * 8;
            GLL(Wbf + (size_t)(n0 + row) * H_ + kt + ce, Bs + c * 16);
        }
    };

    stage(0, 0);
    for (int it = 0; it < 16; it++) {
        const int buf = it & 1;
        if (it < 15) {
            stage(buf ^ 1, (it + 1) * 64);     // issue next tile's loads first
            VMCNT(6);                          // wait only the CURRENT tile's 6
        } else {
            VMCNT(0);
        }
        BARRIER_RAW();                         // all threads' cur-tile GLLs landed
        const bf16_t* As = (const bf16_t*)(psmem + buf * 24576);
        const bf16_t* Bs = (const bf16_t*)(psmem + buf * 24576 + 16384);
#pragma unroll
        for (int h = 0; h < 2; h++) {
            bf16x8 af[4], bfr[2];
#pragma unroll
            for (int im = 0; im < 4; im++)
                af[im] = *(const bf16x8*)&As[(wm * 64 + im * 16 + frow) * 64 + h * 32 + kq];
#pragma unroll
            for (int in = 0; in < 2; in++)
                bfr[in] = *(const bf16x8*)&Bs[(wn * 32 + in * 16 + frow) * 64 + h * 32 + kq];
#pragma unroll
            for (int im = 0; im < 4; im++)
#pragma unroll
                for (int in = 0; in < 2; in++)
                    acc[im][in] = MFMA16(af[im], bfr[in], acc[im][in]);
        }
        LGKM_FENCE();                          // drain ds_reads BEFORE barrier (r12 race)
        BARRIER_RAW();                         // now safe to overwrite this buf
    }

    const int proj = n0 >> 10;
    const int cn = l & 15, cr4 = (l >> 4) * 4;
    const int bb = m0 >> 10, mrem = m0 & 1023;
    const int nn = (n0 & 1023) >> 6;           // head index (tile is 64-aligned)

    if (proj < 2) {
        const float* bias = proj == 0 ? bq : bk;
        bf16_t* bdst = proj == 0 ? Qbf : Kbf;
#pragma unroll
        for (int im = 0; im < 4; im++) {
#pragma unroll
            for (int in = 0; in < 2; in++) {
                int nl = wn * 32 + in * 16 + cn;
                float bsv = bias[(n0 & 1023) + nl];
                int ml = wm * 64 + im * 16 + cr4;
#pragma unroll
                for (int vr = 0; vr < 4; vr++)
                    Es[(ml + vr) * 72 + nl] = (bf16_t)(acc[im][in][vr] + bsv);
            }
        }
        __syncthreads();
        bf16_t* base = bdst + (size_t)(bb * NH_ + nn) * S_ * D_ + (size_t)mrem * D_;
#pragma unroll
        for (int t = 0; t < 4; t++) {
            int c = t * 256 + tid;             // 128 rows x 8 chunks
            int ml = c >> 3, c8 = (c & 7) * 8;
            *(bf16x8*)&base[(size_t)ml * D_ + c8] = *(const bf16x8*)&Es[ml * 72 + c8];
        }
    } else {
        bf16_t* EsV = Es;                      // [64 d][136 m-pad]
#pragma unroll
        for (int im = 0; im < 4; im++) {
#pragma unroll
            for (int in = 0; in < 2; in++) {
                int nl = wn * 32 + in * 16 + cn;   // dd
                float bsv = bv[(n0 & 1023) + nl];
                int ml = wm * 64 + im * 16 + cr4;
                bf16x4 pv = {(bf16_t)(acc[im][in][0] + bsv), (bf16_t)(acc[im][in][1] + bsv),
                             (bf16_t)(acc[im][in][2] + bsv), (bf16_t)(acc[im][in][3] + bsv)};
                *(bf16x4*)&EsV[nl * 136 + ml] = pv;
            }
        }
        __syncthreads();
        bf16_t* base = Vt + (size_t)(bb * NH_ + nn) * D_ * S_ + mrem;
#pragma unroll
        for (int t = 0; t < 4; t++) {
            int c = t * 256 + tid;             // 64 rows(d) x 16 chunks
            int dd = c >> 4, s8 = (c & 15) * 8;
            *(bf16x8*)&base[(size_t)dd * S_ + s8] = *(const bf16x8*)&EsV[dd * 136 + s8];
        }
    }
}

// ---------------------------------------------------------------------------
// MFMA attention — r21: 4 q-tiles per wave (64 q/block), grid 512 = exactly
// 2 blocks/CU of work, matching the measured ~2-resident cap set by the
// unified VGPR+AGPR file (r12: LDS 37.9K still gave 18.5% occupancy — LDS is
// NOT the limiter).  q-tiles/wave is the only lever with a proven positive
// slope (1->2 = -13.7 us, r10): K/V/mask loads amortized 4x, 4 independent
// MFMA streams per wave.  Register budget management:
//  - per-tile {QK(t) -> transform(t)} so only one sac (16 VGPR) is live;
//  - QrLo/QrHi shortcut DELETED: clamped LDS read Qr[row][clamp(off)+64] is
//    exactly equivalent (clamp -64 -> col 0, +64 -> col 128); saves 32 VGPR;
//  - V prefetch after tile-1's transform (~500 cy cover before PV);
//  - 3-publish epilogue (own d-tile in regs) to fit LDS 75264 B (2/CU).
// Tripwires: WRITE_SIZE == 8192 KB exactly (spill -> revert to r10 body),
// VGPR <= 256, dur <= 67 us else revert.
// ---------------------------------------------------------------------------
__global__ __launch_bounds__(256, 2) void attn_mfma_kernel(
        const bf16_t* __restrict__ Qbf, const bf16_t* __restrict__ Kbf,
        const bf16_t* __restrict__ Vt,  const bf16_t* __restrict__ tab_bf,
        const bf16_t* __restrict__ tabT_bf, const float* __restrict__ tab,
        const float* __restrict__ mask, float* __restrict__ out) {
    // aliased region: loop phase = PlsA 4x64x72 bf16 (36864 B) + Qr 64x136
    // bf16 (17408 B) = 54272 B; epilogue = OshF 12x64x17 f32 (52224 B).
    __shared__ __align__(16) char reg0[54272];
    __shared__ __align__(16) bf16_t Pb[64 * QRSTR];       // 17.4 KB
    __shared__ float Ptail[64][2];                        // 0.5 KB
    __shared__ float SArr[4][64][3];                      // 3 KB

    bf16_t* PlsAall = (bf16_t*)reg0;                      // [4][64*PSTR]
    bf16_t* Qr = (bf16_t*)(reg0 + 36864);                 // [64*QRSTR]
    float* OshF = (float*)reg0;                           // epilogue alias

    const int tid = threadIdx.x;
    const int w = tid >> 6, l = tid & 63;
    const int lr = l & 15;
    const int lk = (l >> 4) * 8;
    const int reg4 = (l >> 4) * 4;

    const int gid = blockIdx.x;
    const int hl = gid & 31;            // same head -> same XCD (L2 locality)
    const int qquad = gid >> 5;         // 0..15
    const int b = hl >> 4, h = hl & 15;
    const int q0 = qquad * 64;          // tiles at q0 + t*16, t = 0..3

    const size_t bh = (size_t)(b * NH_ + h);
    const bf16_t* Qh = Qbf + bh * S_ * D_;
    const bf16_t* Kh = Kbf + bh * S_ * D_;
    const bf16_t* Vh = Vt + bh * D_ * S_;
    const float* mrow = mask + b * S_;
    bf16_t* myP = PlsAall + w * 64 * PSTR;

    // zero Pb + Ptail
    for (int e = tid; e < 64 * QRSTR / 2; e += 256) ((unsigned*)Pb)[e] = 0u;
    if (tid < 64) { Ptail[tid][0] = 0.f; Ptail[tid][1] = 0.f; }

    // Q A-frags for 4 tiles (same addresses in all waves -> L1 hits)
    bf16x8 afr[4][2];
#pragma unroll
    for (int t = 0; t < 4; t++) {
        afr[t][0] = *(const bf16x8*)&Qh[(size_t)(q0 + t * 16 + lr) * D_ + lk];
        afr[t][1] = *(const bf16x8*)&Qh[(size_t)(q0 + t * 16 + lr) * D_ + 32 + lk];
    }

    // Qr[i][r] = q_i . tab[r] for 64 rows, n-tiles split across waves
    for (int nt = w; nt < 9; nt += 4) {
        const bf16_t* tb = tab_bf + (size_t)(nt * 16 + lr) * D_;
        bf16x8 t0 = *(const bf16x8*)&tb[lk];
        bf16x8 t1 = *(const bf16x8*)&tb[32 + lk];
        int col = nt * 16 + lr;
#pragma unroll
        for (int t = 0; t < 4; t++) {
            f32x4 qa = {0.f, 0.f, 0.f, 0.f};
            qa = MFMA16(afr[t][0], t0, qa);
            qa = MFMA16(afr[t][1], t1, qa);
            if (col <= 128) {
#pragma unroll
                for (int r = 0; r < 4; r++)
                    Qr[(t * 16 + reg4 + r) * QRSTR + col] = (bf16_t)qa[r];
            }
        }
    }
    __syncthreads();

    f32x4 oacc[4][5] = {};   // [q-tile][4 d-tiles + stats]
    const int kbase = w * 256;

    for (int kt = 0; kt < 4; kt++) {
        const int k0 = kbase + kt * 64;

        float mj[4];
#pragma unroll
        for (int nt = 0; nt < 4; nt++) mj[nt] = mrow[k0 + nt * 16 + lr];

        bf16x8 kfA[4], kfB[4];
#pragma unroll
        for (int nt = 0; nt < 4; nt++)
            kfA[nt] = *(const bf16x8*)&Kh[(size_t)(k0 + nt * 16 + lr) * D_ + lk];
#pragma unroll
        for (int nt = 0; nt < 4; nt++)
            kfB[nt] = *(const bf16x8*)&Kh[(size_t)(k0 + nt * 16 + lr) * D_ + 32 + lk];

        bf16x8 vf[8];

        // per-tile QK -> transform (one sac live at a time)
#pragma unroll
        for (int t = 0; t < 4; t++) {
            const int qa0 = q0 + t * 16;
            const bool allLo = (k0 + 63 - qa0 <= -64);
            const bool allHi = (k0 - (qa0 + 15) >= 64);
            const bool mixed = !(allLo || allHi);

            f32x4 sac[4] = {};
#pragma unroll
            for (int nt = 0; nt < 4; nt++) sac[nt] = MFMA16(afr[t][0], kfA[nt], sac[nt]);
#pragma unroll
            for (int nt = 0; nt < 4; nt++) sac[nt] = MFMA16(afr[t][1], kfB[nt], sac[nt]);

#pragma unroll
            for (int nt = 0; nt < 4; nt++) {
                int gj = k0 + nt * 16 + lr;
#pragma unroll
                for (int r = 0; r < 4; r++) {
                    int gi = qa0 + reg4 + r;
                    int off = gj - gi;
                    int offc = off < -64 ? -64 : (off > 64 ? 64 : off);
                    float rel = (float)Qr[(t * 16 + reg4 + r) * QRSTR + offc + 64];
                    float p = __expf((sac[nt][r] + rel) * 0.125f + mj[nt]);
                    if (mixed) {
                        if (off <= -64)      atomicAdd(&Ptail[t * 16 + reg4 + r][0], p);
                        else if (off >= 64)  atomicAdd(&Ptail[t * 16 + reg4 + r][1], p);
                        else                 Pb[(t * 16 + reg4 + r) * QRSTR + off + 64] = (bf16_t)p;
                    }
                    myP[(t * 16 + reg4 + r) * PSTR + nt * 16 + lr] = (bf16_t)p;
                }
            }

            // V prefetch after tile 1: covers tiles 2-3's transforms (~500cy)
            if (t == 1) {
#pragma unroll
                for (int nt = 0; nt < 4; nt++) {
                    const bf16_t* vb = Vh + (size_t)(nt * 16 + lr) * S_ + k0;
                    vf[2 * nt]     = *(const bf16x8*)&vb[lk];
                    vf[2 * nt + 1] = *(const bf16x8*)&vb[32 + lk];
                }
            }
        }
        LGKM_FENCE();

        // PV per tile
#pragma unroll
        for (int t = 0; t < 4; t++) {
            const int qa0 = q0 + t * 16;
            const bool allLo = (k0 + 63 - qa0 <= -64);
            const bool allHi = (k0 - (qa0 + 15) >= 64);
            float ov = (lr == 0) ? 1.f : (lr == 1) ? (allLo ? 1.f : 0.f)
                     : (lr == 2) ? (allHi ? 1.f : 0.f) : 0.f;
            bf16_t ob = (bf16_t)ov;
            bf16x8 onesf = {ob, ob, ob, ob, ob, ob, ob, ob};

            bf16x8 pa0 = *(const bf16x8*)&myP[(t * 16 + lr) * PSTR + lk];
            bf16x8 pa1 = *(const bf16x8*)&myP[(t * 16 + lr) * PSTR + 32 + lk];
#pragma unroll
            for (int nt = 0; nt < 4; nt++) {
                oacc[t][nt] = MFMA16(pa0, vf[2 * nt], oacc[t][nt]);
                oacc[t][nt] = MFMA16(pa1, vf[2 * nt + 1], oacc[t][nt]);
            }
            oacc[t][4] = MFMA16(pa0, onesf, oacc[t][4]);
            oacc[t][4] = MFMA16(pa1, onesf, oacc[t][4]);
        }
    }

    // all waves done reading myP/Qr before OshF overwrites the aliased region
    __syncthreads();

    // partials: stats + the 3 d-tiles this wave does NOT own
    if (lr < 3) {
#pragma unroll
        for (int t = 0; t < 4; t++)
#pragma unroll
            for (int r = 0; r < 4; r++)
                SArr[w][t * 16 + reg4 + r][lr] = oacc[t][4][r];
    }
    float ownv[4][4];
#pragma unroll
    for (int nt = 0; nt < 4; nt++) {
        if (nt == w) {
#pragma unroll
            for (int t = 0; t < 4; t++)
#pragma unroll
                for (int r = 0; r < 4; r++) ownv[t][r] = oacc[t][nt][r];
        } else {
            int slot = nt - (nt > w ? 1 : 0);
#pragma unroll
            for (int t = 0; t < 4; t++)
#pragma unroll
                for (int r = 0; r < 4; r++)
                    OshF[((w * 3 + slot) * 64 + t * 16 + reg4 + r) * OSTR + lr] = oacc[t][nt][r];
        }
    }
    __syncthreads();

    // wave w owns d-tile w for all 4 q-tiles: own regs + 3 published partials
#pragma unroll
    for (int t = 0; t < 4; t++) {
        f32x4 c = {};
#pragma unroll
        for (int r = 0; r < 4; r++) c[r] = ownv[t][r];
#pragma unroll
        for (int w2 = 0; w2 < 4; w2++) {
            if (w2 != w) {
                int slot = w - (w > w2 ? 1 : 0);
#pragma unroll
                for (int r = 0; r < 4; r++)
                    c[r] += OshF[((w2 * 3 + slot) * 64 + t * 16 + reg4 + r) * OSTR + lr];
            }
        }
#pragma unroll
        for (int kc = 0; kc < 4; kc++) {
            bf16x8 pa = *(const bf16x8*)&Pb[(t * 16 + lr) * QRSTR + kc * 32 + lk];
            bf16x8 tb = *(const bf16x8*)&tabT_bf[(size_t)(w * 16 + lr) * 128 + kc * 32 + lk];
            c = MFMA16(pa, tb, c);
        }
#pragma unroll
        for (int r = 0; r < 4; r++) {
            int row = t * 16 + reg4 + r, gi = q0 + row;
            float ls  = SArr[0][row][0] + SArr[1][row][0] + SArr[2][row][0] + SArr[3][row][0];
            float plo = SArr[0][row][1] + SArr[1][row][1] + SArr[2][row][1] + SArr[3][row][1]
                      + Ptail[row][0];
            float phi = SArr[0][row][2] + SArr[1][row][2] + SArr[2][row][2] + SArr[3][row][2]
                      + Ptail[row][1];
            int d = w * 16 + lr;
            float o = c[r] + plo * tab[d] + phi * tab[128 * D_ + d];
            out[((size_t)(b * S_ + gi) * NH_ + h) * D_ + d] = o / ls;
        }
    }
}

// ---------------------------------------------------------------------------
extern "C" void kernel_launch(void* const* d_in, const int* in_sizes, int n_in,
                              void* d_out, int out_size, void* d_ws, size_t ws_size,
                              hipStream_t stream) {
    const float* hidden = (const float*)d_in[0];
    const float* mask   = (const float*)d_in[1];
    const float* Wq     = (const float*)d_in[2];
    const float* bq     = (const float*)d_in[3];
    const float* Wk     = (const float*)d_in[4];
    const float* bk     = (const float*)d_in[5];
    const float* Wv     = (const float*)d_in[6];
    const float* bv     = (const float*)d_in[7];
    float* out = (float*)d_out;

    char* wsb = (char*)d_ws;
    bf16_t* Qbf    = (bf16_t*)(wsb);                                // 4 MB
    bf16_t* Kbf    = (bf16_t*)(wsb + (4u << 20));                   // 4 MB
    bf16_t* Vt     = (bf16_t*)(wsb + (8u << 20));                   // 4 MB
    float*  tab    = (float*) (wsb + (12u << 20));                  // 33 KB
    bf16_t* tab_bf = (bf16_t*)(wsb + (12u << 20) + (64u << 10));    // 18.4 KB
    bf16_t* tabT   = (bf16_t*)(wsb + (12u << 20) + (96u << 10));    // 16 KB
    bf16_t* hidbf  = (bf16_t*)(wsb + (12u << 20) + (128u << 10));   // 4 MB
    bf16_t* wbf    = (bf16_t*)(wsb + (16u << 20) + (128u << 10));   // 6 MB

    cast_tab_kernel<<<dim3(5156), dim3(256), 0, stream>>>(
        hidden, Wq, Wk, Wv, hidbf, wbf, tab, tab_bf, tabT);

    proj_mfma_kernel<<<dim3(768), dim3(256), 0, stream>>>(
        hidbf, wbf, bq, bk, bv, Qbf, Kbf, Vt);

    attn_mfma_kernel<<<dim3((S_ / 64) * NH_ * B_), dim3(256), 0, stream>>>(
        Qbf, Kbf, Vt, tab_bf, tabT, tab, mask, out);
}